// Round 3
// baseline (277.339 us; speedup 1.0000x reference)
//
#include <hip/hip_runtime.h>
#include <hip/hip_fp16.h>
#include <math.h>

// AmpNorm via real-input 2D FFT (half spectrum, fp16 intermediate) on MI355X.
// x [32,3,384,384] f32; running_amp [3,384,384] f32 (all-zero in bench -> adopt branch).
// Half spectrum A: [96][384][PADW=200] __half2 (w=0..192 valid, 193..199 zero).
// FFT: 384 = 3*4*4*4*2 Stockham (radix 3,4,4,4,2), SINGLE LDS buffer
// (regs->sync->write->sync per stage), 8 lines per 256-thread block.

#define NFFT   384
#define NL     8
#define LSTR   385        // LDS line stride in float2
#define PADW   200        // padded half-spectrum width (193 valid)
#define HPLANE (NFFT * PADW)   // 76800 elements per image half-plane
#define PLANE  147456     // 384*384
#define IMGS   96

__device__ __forceinline__ float2 cmul(float2 a, float2 b) {
    return make_float2(a.x*b.x - a.y*b.y, a.x*b.y + a.y*b.x);
}

__device__ __forceinline__ void fill_tw(float2* tw) {
    for (int k = threadIdx.x; k < NFFT; k += 256) {
        float ang = (-6.28318530717958647692f / (float)NFFT) * (float)k;
        float sv, cv;
        sincosf(ang, &sv, &cv);
        tw[k] = make_float2(cv, sv);   // exp(-2*pi*i*k/384)
    }
}

// Single-buffer Stockham FFT of one 384-line held in s[0..383] (stride-1, line-local).
// Stages: r3(m=1), r4(m=3), r4(m=12), r4(m=48), r2(m=192, twiddle-free, in-place).
// Caller must __syncthreads() after staging writes, before calling.
// Ends with a __syncthreads() (result in s, natural order).
template<int DIR>
__device__ void fft_sb(float2* s, const float2* tw, int lane) {
    const float dir = (float)DIR;
    float2 r[12];

    // ---- radix-3, m=1 ----
    #pragma unroll
    for (int i = 0; i < 4; ++i) {
        int j = lane + 32 * i;
        r[3*i]   = s[j];
        r[3*i+1] = s[j + 128];
        r[3*i+2] = s[j + 256];
    }
    __syncthreads();
    {
        const float b3 = (DIR > 0) ? -0.86602540378443864676f : 0.86602540378443864676f;
        #pragma unroll
        for (int i = 0; i < 4; ++i) {
            int j = lane + 32 * i;
            float2 c0 = r[3*i], c1 = r[3*i+1], c2 = r[3*i+2];
            float2 t0 = make_float2(c1.x + c2.x, c1.y + c2.y);
            float2 dd = make_float2(c1.x - c2.x, c1.y - c2.y);
            float2 y0 = make_float2(c0.x + t0.x, c0.y + t0.y);
            float2 u1 = make_float2(c0.x - 0.5f * t0.x, c0.y - 0.5f * t0.y);
            float2 iv = make_float2(-b3 * dd.y, b3 * dd.x);
            float2 y1 = make_float2(u1.x + iv.x, u1.y + iv.y);
            float2 y2 = make_float2(u1.x - iv.x, u1.y - iv.y);
            float2 w1 = tw[j];      w1.y *= dir;
            float2 w2 = tw[2 * j];  w2.y *= dir;
            s[3 * j]     = y0;
            s[3 * j + 1] = cmul(w1, y1);
            s[3 * j + 2] = cmul(w2, y2);
        }
    }
    __syncthreads();

    // ---- radix-4 stages: m = 3, 12, 48 ----
    #pragma unroll
    for (int st = 0; st < 3; ++st) {
        const int m = 3 << (2 * st);
        #pragma unroll
        for (int i = 0; i < 3; ++i) {
            int q = lane + 32 * i;
            r[4*i]   = s[q];
            r[4*i+1] = s[q + 96];
            r[4*i+2] = s[q + 192];
            r[4*i+3] = s[q + 288];
        }
        __syncthreads();
        #pragma unroll
        for (int i = 0; i < 3; ++i) {
            int q  = lane + 32 * i;          // [0,96) = j*m + k
            int k  = q % m;
            int jm = q - k;
            float2 a = r[4*i], b = r[4*i+1], c = r[4*i+2], e = r[4*i+3];
            float2 acp = make_float2(a.x + c.x, a.y + c.y);
            float2 acm = make_float2(a.x - c.x, a.y - c.y);
            float2 bdp = make_float2(b.x + e.x, b.y + e.y);
            float2 bdm = make_float2(b.x - e.x, b.y - e.y);
            float2 ibd = make_float2(-dir * bdm.y, dir * bdm.x);
            float2 y0 = make_float2(acp.x + bdp.x, acp.y + bdp.y);
            float2 y2 = make_float2(acp.x - bdp.x, acp.y - bdp.y);
            float2 y1 = make_float2(acm.x - ibd.x, acm.y - ibd.y);
            float2 y3 = make_float2(acm.x + ibd.x, acm.y + ibd.y);
            float2 w1 = tw[jm];      w1.y *= dir;
            float2 w2 = tw[2 * jm];  w2.y *= dir;
            float2 w3 = tw[3 * jm];  w3.y *= dir;
            s[4 * jm + k]         = y0;
            s[4 * jm + k + m]     = cmul(w1, y1);
            s[4 * jm + k + 2 * m] = cmul(w2, y2);
            s[4 * jm + k + 3 * m] = cmul(w3, y3);
        }
        __syncthreads();
    }

    // ---- radix-2, m=192: twiddle-free, per-thread in-place ----
    #pragma unroll
    for (int i = 0; i < 6; ++i) {
        int q = lane + 32 * i;
        float2 a = s[q];
        float2 b = s[q + 192];
        s[q]       = make_float2(a.x + b.x, a.y + b.y);
        s[q + 192] = make_float2(a.x - b.x, a.y - b.y);
    }
    __syncthreads();
}

// ---- K1: forward row FFT, two real rows packed per complex FFT; half spectrum out (fp16) ----
__global__ __launch_bounds__(256, 5) void k_fft_rows_fwd(const float* __restrict__ x,
                                                         __half2* __restrict__ A) {
    __shared__ float2 tw[NFFT];
    __shared__ float2 b0[NL * LSTR];
    int bx  = blockIdx.x;
    int img = bx / 24;
    int rg  = bx - img * 24;
    fill_tw(tw);
    int line = threadIdx.x >> 5, lane = threadIdx.x & 31;
    int pr   = rg * NL + line;              // row-pair index [0,192)
    const float* xa = x + (size_t)img * PLANE + (size_t)(2 * pr) * NFFT;
    const float* xb = xa + NFFT;
    float2* s = b0 + line * LSTR;
    #pragma unroll
    for (int i = 0; i < 12; ++i) {
        int col = lane + 32 * i;
        s[col] = make_float2(xa[col], xb[col]);
    }
    __syncthreads();
    fft_sb<1>(s, tw, lane);
    __half2* Aa = A + ((size_t)img * NFFT + 2 * pr) * PADW;
    __half2* Ab = Aa + PADW;
    #pragma unroll
    for (int i = 0; i < 7; ++i) {
        int w = lane + 32 * i;
        if (w <= 192) {
            float2 Z  = s[w];
            float2 Zm = s[w == 0 ? 0 : NFFT - w];
            Aa[w] = __floats2half2_rn(0.5f * (Z.x + Zm.x),  0.5f * (Z.y - Zm.y));
            Ab[w] = __floats2half2_rn(0.5f * (Z.y + Zm.y), -0.5f * (Z.x - Zm.x));
        }
    }
    if (lane < 7) {   // zero the pad columns
        Aa[193 + lane] = __floats2half2_rn(0.0f, 0.0f);
        Ab[193 + lane] = __floats2half2_rn(0.0f, 0.0f);
    }
}

// ---- K2: forward column FFT on half spectrum, in place (fp16) ----
__global__ __launch_bounds__(256, 5) void k_fft_cols_fwd(__half2* __restrict__ A) {
    __shared__ float2 tw[NFFT];
    __shared__ float2 b0[NL * LSTR];
    int bx  = blockIdx.x;
    int img = bx / 25;
    int cg  = bx - img * 25;
    int w0  = cg * NL;
    fill_tw(tw);
    __half2* Ai = A + (size_t)img * HPLANE;
    #pragma unroll
    for (int i = 0; i < 12; ++i) {
        int idx = i * 256 + threadIdx.x;
        int h = idx >> 3, wc = idx & 7;
        b0[wc * LSTR + h] = __half22float2(Ai[h * PADW + w0 + wc]);
    }
    __syncthreads();
    int line = threadIdx.x >> 5, lane = threadIdx.x & 31;
    fft_sb<1>(b0 + line * LSTR, tw, lane);
    #pragma unroll
    for (int i = 0; i < 12; ++i) {
        int idx = i * 256 + threadIdx.x;
        int h = idx >> 3, wc = idx & 7;
        float2 z = b0[wc * LSTR + h];
        Ai[h * PADW + w0 + wc] = __floats2half2_rn(z.x, z.y);
    }
}

// ---- K3: deterministic sum of running_amp -> flag ----
__global__ __launch_bounds__(256) void k_sum_part(const float* __restrict__ r,
                                                  float* __restrict__ partial) {
    __shared__ float sm[256];
    int t = blockIdx.x * 256 + threadIdx.x;
    sm[threadIdx.x] = r[t];
    __syncthreads();
    for (int s = 128; s > 0; s >>= 1) {
        if (threadIdx.x < s) sm[threadIdx.x] += sm[threadIdx.x + s];
        __syncthreads();
    }
    if (threadIdx.x == 0) partial[blockIdx.x] = sm[0];
}

__global__ __launch_bounds__(256) void k_sum_final(const float* __restrict__ partial,
                                                   float* __restrict__ flag) {
    __shared__ float sm[256];
    float v = 0.0f;
    for (int t = threadIdx.x; t < 1728; t += 256) v += partial[t];
    sm[threadIdx.x] = v;
    __syncthreads();
    for (int s = 128; s > 0; s >>= 1) {
        if (threadIdx.x < s) sm[threadIdx.x] += sm[threadIdx.x + s];
        __syncthreads();
    }
    if (threadIdx.x == 0) flag[0] = sm[0];
}

// ---- K4: batch-mean amplitude on half spectrum (pads read as zero -> amp 0) ----
__global__ __launch_bounds__(256) void k_amp(const __half2* __restrict__ A,
                                             float* __restrict__ amp) {
    int t = blockIdx.x * 256 + threadIdx.x;    // [0, 3*76800)
    int c  = t / HPLANE;
    int hw = t - c * HPLANE;
    float s = 0.0f;
    #pragma unroll 4
    for (int b = 0; b < 32; ++b) {
        float2 z = __half22float2(A[(size_t)(b * 3 + c) * HPLANE + hw]);
        s += sqrtf(z.x * z.x + z.y * z.y);
    }
    amp[t] = s * (1.0f / 32.0f);
}

// ---- K5: scale F <- new_amp * F/|F|, fused into inverse column FFT ----
__global__ __launch_bounds__(256, 5) void k_ifft_cols_scale(__half2* __restrict__ A,
                                                            const float* __restrict__ ampm,
                                                            const float* __restrict__ running,
                                                            const float* __restrict__ flag) {
    __shared__ float2 tw[NFFT];
    __shared__ float2 b0[NL * LSTR];
    int bx  = blockIdx.x;
    int img = bx / 25;
    int cg  = bx - img * 25;
    int w0  = cg * NL;
    int c   = img % 3;
    fill_tw(tw);
    bool adopt = (flag[0] == 0.0f);
    __half2* Ai = A + (size_t)img * HPLANE;
    #pragma unroll
    for (int i = 0; i < 12; ++i) {
        int idx = i * 256 + threadIdx.x;
        int h = idx >> 3, wc = idx & 7;
        int w = w0 + wc;
        float2 z  = __half22float2(Ai[h * PADW + w]);
        float  am = ampm[(size_t)c * HPLANE + h * PADW + w];
        float  na;
        if (adopt) na = am;
        else {
            int wr = (w < NFFT) ? w : 0;   // EMA branch never taken in bench (running==0)
            na = 0.9f * running[((size_t)c * NFFT + h) * NFFT + wr] + 0.1f * am;
        }
        float mag = sqrtf(z.x * z.x + z.y * z.y);
        float2 zn;
        if (mag > 0.0f) {
            float sc = na / mag;
            zn = make_float2(z.x * sc, z.y * sc);
        } else {
            zn = make_float2(na, 0.0f);
        }
        b0[wc * LSTR + h] = zn;
    }
    __syncthreads();
    int line = threadIdx.x >> 5, lane = threadIdx.x & 31;
    fft_sb<-1>(b0 + line * LSTR, tw, lane);
    const float inv = 1.0f / (float)NFFT;
    #pragma unroll
    for (int i = 0; i < 12; ++i) {
        int idx = i * 256 + threadIdx.x;
        int h = idx >> 3, wc = idx & 7;
        float2 z = b0[wc * LSTR + h];
        Ai[h * PADW + w0 + wc] = __floats2half2_rn(z.x * inv, z.y * inv);
    }
}

// ---- K6: inverse row FFT (C2R), two real rows per complex FFT ----
__global__ __launch_bounds__(256, 5) void k_ifft_rows_out(const __half2* __restrict__ A,
                                                          float* __restrict__ out) {
    __shared__ float2 tw[NFFT];
    __shared__ float2 b0[NL * LSTR];
    int bx  = blockIdx.x;
    int img = bx / 24;
    int rg  = bx - img * 24;
    fill_tw(tw);
    int line = threadIdx.x >> 5, lane = threadIdx.x & 31;
    int pr   = rg * NL + line;
    const __half2* Aa = A + ((size_t)img * NFFT + 2 * pr) * PADW;
    const __half2* Ab = Aa + PADW;
    float2* s = b0 + line * LSTR;
    #pragma unroll
    for (int i = 0; i < 7; ++i) {
        int w = lane + 32 * i;
        if (w <= 192) {
            float2 Fa = __half22float2(Aa[w]);
            float2 Fb = __half22float2(Ab[w]);
            s[w] = make_float2(Fa.x - Fb.y, Fa.y + Fb.x);            // Z(w) = Fa + i*Fb
            if (w >= 1 && w <= 191)
                s[NFFT - w] = make_float2(Fa.x + Fb.y, Fb.x - Fa.y); // conj(Fa) + i*conj(Fb)
        }
    }
    __syncthreads();
    fft_sb<-1>(s, tw, lane);
    const float inv = 1.0f / (float)NFFT;
    float* oa = out + (size_t)img * PLANE + (size_t)(2 * pr) * NFFT;
    float* ob = oa + NFFT;
    #pragma unroll
    for (int i = 0; i < 12; ++i) {
        int col = lane + 32 * i;
        float2 z = s[col];
        oa[col] = z.x * inv;
        ob[col] = z.y * inv;
    }
}

extern "C" void kernel_launch(void* const* d_in, const int* in_sizes, int n_in,
                              void* d_out, int out_size, void* d_ws, size_t ws_size,
                              hipStream_t stream) {
    const float* x       = (const float*)d_in[0];
    const float* running = (const float*)d_in[1];
    float* out = (float*)d_out;

    char* ws = (char*)d_ws;
    __half2* A    = (__half2*)ws;                       // 96*384*200*4 = 29,491,200 B
    float*   ampm = (float*)(ws + 29491200);            // 3*76800*4   =    921,600 B
    float*   part = (float*)(ws + 29491200 + 921600);   // 1728*4 B
    float*   flag = (float*)(ws + 29491200 + 921600 + 8192);

    k_sum_part<<<1728, 256, 0, stream>>>(running, part);
    k_sum_final<<<1, 256, 0, stream>>>(part, flag);
    k_fft_rows_fwd<<<IMGS * 24, 256, 0, stream>>>(x, A);
    k_fft_cols_fwd<<<IMGS * 25, 256, 0, stream>>>(A);
    k_amp<<<(3 * HPLANE) / 256, 256, 0, stream>>>(A, ampm);
    k_ifft_cols_scale<<<IMGS * 25, 256, 0, stream>>>(A, ampm, running, flag);
    k_ifft_rows_out<<<IMGS * 24, 256, 0, stream>>>(A, out);
}